// Round 2
// baseline (167.992 us; speedup 1.0000x reference)
//
#include <hip/hip_runtime.h>
#include <hip/hip_bf16.h>

// Per-edge dot product: score[e] = dot(x[src[e]], x[dst[e]]), D_FEAT = 128.
// x: [N_NODES,128] f32; src,dst: [E] int32; out: [E] f32.
//
// Round-2 layout: 8 lanes per edge, each lane loads 4 float4s from each row
// (8 lanes x 4 x 16B = 512B = one row). This puts 8 independent 16B gather
// loads in flight per thread (vs 2 in round 1) to hide L3-hit latency, and
// cuts the shuffle reduction from 5 steps to 3 (masks 1,2,4 within the
// 8-lane group). One wave64 handles 8 edges; block=256 handles 32 edges.

__device__ __forceinline__ float dot4(const float4& a, const float4& b) {
  return a.x * b.x + a.y * b.y + a.z * b.z + a.w * b.w;
}

__global__ __launch_bounds__(256) void edge_dot_kernel(
    const float* __restrict__ x,
    const int*   __restrict__ src,
    const int*   __restrict__ dst,
    float*       __restrict__ out,
    int n_edges) {
  const int gtid = blockIdx.x * blockDim.x + threadIdx.x;
  const int edge = gtid >> 3;        // 8 lanes per edge
  const int sub  = threadIdx.x & 7;  // lane within the edge's group
  if (edge >= n_edges) return;

  const size_t s = (size_t)(unsigned)src[edge];
  const size_t d = (size_t)(unsigned)dst[edge];

  const float4* __restrict__ xs =
      reinterpret_cast<const float4*>(x + s * 128) + sub;
  const float4* __restrict__ xd =
      reinterpret_cast<const float4*>(x + d * 128) + sub;

  // 8 independent 16B loads — issue them all before consuming.
  const float4 a0 = xs[0];
  const float4 a1 = xs[8];
  const float4 a2 = xs[16];
  const float4 a3 = xs[24];
  const float4 b0 = xd[0];
  const float4 b1 = xd[8];
  const float4 b2 = xd[16];
  const float4 b3 = xd[24];

  float acc = dot4(a0, b0) + dot4(a1, b1) + dot4(a2, b2) + dot4(a3, b3);

  // Reduce across the 8 lanes of this edge's group.
  acc += __shfl_xor(acc, 1, 64);
  acc += __shfl_xor(acc, 2, 64);
  acc += __shfl_xor(acc, 4, 64);

  if (sub == 0) out[edge] = acc;
}

extern "C" void kernel_launch(void* const* d_in, const int* in_sizes, int n_in,
                              void* d_out, int out_size, void* d_ws, size_t ws_size,
                              hipStream_t stream) {
  const float* x   = (const float*)d_in[0];
  const int*   src = (const int*)d_in[1];
  const int*   dst = (const int*)d_in[2];
  float*       out = (float*)d_out;

  const int n_edges = in_sizes[1];        // 1,200,000
  const int threads = 256;                // 32 edges per block
  const int edges_per_block = threads / 8;
  const int grid = (n_edges + edges_per_block - 1) / edges_per_block;

  edge_dot_kernel<<<grid, threads, 0, stream>>>(x, src, dst, out, n_edges);
}